// Round 3
// baseline (392.837 us; speedup 1.0000x reference)
//
#include <hip/hip_runtime.h>

#define B_TOT 8192
#define T_LEN 1024
#define HID 10

typedef float v2f __attribute__((ext_vector_type(2)));

// One batch element per 16-lane group (lanes 0..9 active: one hidden unit each).
// Weights in registers; h broadcast within group via shfl; gates packed (i,f),(g,o)
// to use v_pk_fma_f32; activations via raw v_exp_f32/v_rcp_f32 (1-ulp, saturating).
__global__ __launch_bounds__(256) void lstm_fused_kernel(
    const float* __restrict__ x,      // [B, T]
    const float* __restrict__ W_ih,   // [40, 1]
    const float* __restrict__ W_hh,   // [40, 10]  row-major, gate order i,f,g,o
    const float* __restrict__ b_ih,   // [40]
    const float* __restrict__ b_hh,   // [40]
    const float* __restrict__ W_lin,  // [1, 10]
    const float* __restrict__ b_lin,  // [1]
    float* __restrict__ out)          // [B]
{
    const int tid  = threadIdx.x;
    const int j16  = tid & 15;                    // lane within 16-group
    const int b    = blockIdx.x * 16 + (tid >> 4);
    const bool act = (j16 < HID);
    const int j    = act ? j16 : 0;               // clamp idle lanes (harmless work)

    // Per-lane weights, packed by gate pair: this lane owns hidden unit j.
    v2f w01[HID], w23[HID];   // (W_i[k], W_f[k]) and (W_g[k], W_o[k])
    v2f wi01, wi23, b01, b23;
    {
        const int r0 = 0 * HID + j, r1 = 1 * HID + j;
        const int r2 = 2 * HID + j, r3 = 3 * HID + j;
        wi01 = (v2f){W_ih[r0], W_ih[r1]};
        wi23 = (v2f){W_ih[r2], W_ih[r3]};
        b01  = (v2f){b_ih[r0] + b_hh[r0], b_ih[r1] + b_hh[r1]};
        b23  = (v2f){b_ih[r2] + b_hh[r2], b_ih[r3] + b_hh[r3]};
#pragma unroll
        for (int k = 0; k < HID; ++k) {
            w01[k] = (v2f){W_hh[r0 * HID + k], W_hh[r1 * HID + k]};
            w23[k] = (v2f){W_hh[r2 * HID + k], W_hh[r3 * HID + k]};
        }
    }
    const float wl = act ? W_lin[j] : 0.0f;

    float h = 0.0f, c = 0.0f;
    const float* xb = x + (size_t)b * T_LEN;

    const float LOG2E  = 1.442695040888963f;   // log2(e)
    const float LOG2E2 = 2.885390081777927f;   // 2*log2(e)
    const v2f mneg = (v2f){-LOG2E, -LOG2E};    // for (i,f) sigmoid args
    const v2f mgo  = (v2f){LOG2E2, -LOG2E};    // g: tanh arg scale; o: sigmoid

    // one LSTM step on scalar input xv
#define LSTM_STEP(xv)                                                          \
    {                                                                          \
        v2f xv2 = (v2f){(xv), (xv)};                                           \
        v2f a01 = __builtin_elementwise_fma(xv2, wi01, b01);                   \
        v2f a23 = __builtin_elementwise_fma(xv2, wi23, b23);                   \
        _Pragma("unroll")                                                      \
        for (int k = 0; k < HID; ++k) {                                        \
            float hk = __shfl(h, k, 16);                                       \
            v2f hk2 = (v2f){hk, hk};                                           \
            a01 = __builtin_elementwise_fma(w01[k], hk2, a01);                 \
            a23 = __builtin_elementwise_fma(w23[k], hk2, a23);                 \
        }                                                                      \
        v2f m01 = a01 * mneg;   /* (-λ·ai, -λ·af) */                           \
        v2f m23 = a23 * mgo;    /* (2λ·ag, -λ·ao) */                           \
        float ei = __builtin_amdgcn_exp2f(m01.x);                              \
        float ef = __builtin_amdgcn_exp2f(m01.y);                              \
        float eg = __builtin_amdgcn_exp2f(m23.x);                              \
        float eo = __builtin_amdgcn_exp2f(m23.y);                              \
        float ig = __builtin_amdgcn_rcpf(1.0f + ei);  /* sigmoid(ai) */        \
        float fg = __builtin_amdgcn_rcpf(1.0f + ef);                           \
        float og = __builtin_amdgcn_rcpf(1.0f + eo);                           \
        float rg = __builtin_amdgcn_rcpf(1.0f + eg);                           \
        float gg = fmaf(-2.0f, rg, 1.0f);             /* tanh(ag) */           \
        c = fmaf(fg, c, ig * gg);                                              \
        float ec = __builtin_amdgcn_exp2f(c * LOG2E2);                         \
        float tc = fmaf(-2.0f, __builtin_amdgcn_rcpf(1.0f + ec), 1.0f);        \
        h = og * tc;                                                           \
    }

    float4 xq = *reinterpret_cast<const float4*>(xb);   // steps 0..3
    for (int t = 0; t < T_LEN; t += 4) {
        float4 xn = make_float4(0.f, 0.f, 0.f, 0.f);
        if (t + 4 < T_LEN)
            xn = *reinterpret_cast<const float4*>(xb + t + 4);  // prefetch
        LSTM_STEP(xq.x)
        LSTM_STEP(xq.y)
        LSTM_STEP(xq.z)
        LSTM_STEP(xq.w)
        xq = xn;
    }
#undef LSTM_STEP

    // out[b] = dot(c, W_lin) + b_lin   (reduce across the 16-lane group)
    float v = act ? c * wl : 0.0f;
#pragma unroll
    for (int s = 1; s < 16; s <<= 1) v += __shfl_xor(v, s, 16);
    if (j16 == 0) out[b] = v + b_lin[0];
}

extern "C" void kernel_launch(void* const* d_in, const int* in_sizes, int n_in,
                              void* d_out, int out_size, void* d_ws, size_t ws_size,
                              hipStream_t stream) {
    const float* x     = (const float*)d_in[0];
    const float* W_ih  = (const float*)d_in[1];
    const float* W_hh  = (const float*)d_in[2];
    const float* b_ih  = (const float*)d_in[3];
    const float* b_hh  = (const float*)d_in[4];
    const float* W_lin = (const float*)d_in[5];
    const float* b_lin = (const float*)d_in[6];
    float* out = (float*)d_out;

    // 16 batch elements per 256-thread block -> 512 blocks, 2048 waves (2/SIMD).
    dim3 grid(B_TOT / 16), block(256);
    hipLaunchKernelGGL(lstm_fused_kernel, grid, block, 0, stream,
                       x, W_ih, W_hh, b_ih, b_hh, W_lin, b_lin, out);
}

// Round 4
// 356.703 us; speedup vs baseline: 1.1013x; 1.1013x over previous
//
#include <hip/hip_runtime.h>

#define B_TOT 8192
#define T_LEN 1024
#define HID 10

typedef float v2f __attribute__((ext_vector_type(2)));

// One batch element per 16-lane group (lanes 0..9 active: one hidden unit each).
// h broadcast via DPP row_newbcast (pure VALU, no LDS pipe). Gates packed (i,f),(g,o)
// for v_pk_fma_f32. Weights pre-scaled by exp2 args; cell state kept as C = 2*log2(e)*c.
// Activations via raw v_exp_f32 / v_rcp_f32 (saturate correctly at +-inf).

// Broadcast lane K (0..15) of each row-of-16 to the whole row. K must be a literal.
#define BCAST16(v, K)                                                         \
    __int_as_float(__builtin_amdgcn_update_dpp(                               \
        __float_as_int(v), __float_as_int(v), 0x150 | (K), 0xF, 0xF, false))

__global__ __launch_bounds__(256) void lstm_fused_kernel(
    const float* __restrict__ x,      // [B, T]
    const float* __restrict__ W_ih,   // [40, 1]
    const float* __restrict__ W_hh,   // [40, 10]  gate order i,f,g,o
    const float* __restrict__ b_ih,   // [40]
    const float* __restrict__ b_hh,   // [40]
    const float* __restrict__ W_lin,  // [1, 10]
    const float* __restrict__ b_lin,  // [1]
    float* __restrict__ out)          // [B]
{
    const int tid  = threadIdx.x;
    const int j16  = tid & 15;                    // lane within 16-group
    const int b    = blockIdx.x * 16 + (tid >> 4);
    const bool act = (j16 < HID);
    const int j    = act ? j16 : 0;               // idle lanes do harmless clamped work

    const float NL = -1.4426950408889634f;        // -log2(e)  (sigmoid gates i,f,o)
    const float TL =  2.8853900817779268f;        // 2*log2(e) (tanh gate g, C scaling)

    // Per-lane pre-scaled weights, packed by gate pair (i,f) and (g,o).
    v2f w01[HID], w23[HID];
    v2f wi01, wi23, b01, b23;
    {
        const int r0 = 0 * HID + j, r1 = 1 * HID + j;
        const int r2 = 2 * HID + j, r3 = 3 * HID + j;
        wi01 = (v2f){NL * W_ih[r0], NL * W_ih[r1]};
        wi23 = (v2f){TL * W_ih[r2], NL * W_ih[r3]};
        b01  = (v2f){NL * (b_ih[r0] + b_hh[r0]), NL * (b_ih[r1] + b_hh[r1])};
        b23  = (v2f){TL * (b_ih[r2] + b_hh[r2]), NL * (b_ih[r3] + b_hh[r3])};
#pragma unroll
        for (int k = 0; k < HID; ++k) {
            w01[k] = (v2f){NL * W_hh[r0 * HID + k], NL * W_hh[r1 * HID + k]};
            w23[k] = (v2f){TL * W_hh[r2 * HID + k], NL * W_hh[r3 * HID + k]};
        }
    }
    // out = sum_j c_j*W_lin_j + b_lin; c = C/(2*log2 e) -> fold into wl.
    const float wl = act ? W_lin[j] * 0.34657359027997264f : 0.0f;

    float h = 0.0f, C = 0.0f;
    const float* xb = x + (size_t)b * T_LEN;

#define ACC(K, A01, A23)                                                      \
    {                                                                         \
        float hk = BCAST16(h, K);                                             \
        v2f hk2 = (v2f){hk, hk};                                              \
        A01 = __builtin_elementwise_fma(w01[K], hk2, A01);                    \
        A23 = __builtin_elementwise_fma(w23[K], hk2, A23);                    \
    }

#define LSTM_STEP(xv)                                                         \
    {                                                                         \
        v2f xv2 = (v2f){(xv), (xv)};                                          \
        v2f a01 = __builtin_elementwise_fma(xv2, wi01, b01);                  \
        v2f a23 = __builtin_elementwise_fma(xv2, wi23, b23);                  \
        v2f s01 = (v2f){0.0f, 0.0f}, s23 = (v2f){0.0f, 0.0f};                 \
        ACC(0, a01, a23) ACC(1, a01, a23) ACC(2, a01, a23)                    \
        ACC(3, a01, a23) ACC(4, a01, a23)                                     \
        ACC(5, s01, s23) ACC(6, s01, s23) ACC(7, s01, s23)                    \
        ACC(8, s01, s23) ACC(9, s01, s23)                                     \
        a01 += s01;                                                           \
        a23 += s23;                                                           \
        float ig = __builtin_amdgcn_rcpf(1.0f + __builtin_amdgcn_exp2f(a01.x)); \
        float fg = __builtin_amdgcn_rcpf(1.0f + __builtin_amdgcn_exp2f(a01.y)); \
        float rg = __builtin_amdgcn_rcpf(1.0f + __builtin_amdgcn_exp2f(a23.x)); \
        float og = __builtin_amdgcn_rcpf(1.0f + __builtin_amdgcn_exp2f(a23.y)); \
        float gg = fmaf(-2.0f * TL, rg, TL);   /* 2L*tanh(g_raw) */           \
        C = fmaf(fg, C, ig * gg);                                             \
        float tc = fmaf(-2.0f,                                                \
                        __builtin_amdgcn_rcpf(1.0f + __builtin_amdgcn_exp2f(C)), \
                        1.0f);                                                \
        h = og * tc;                                                          \
    }

    float4 xq = *reinterpret_cast<const float4*>(xb);   // steps 0..3
    int t = 0;
    for (; t < T_LEN - 4; t += 4) {
        float4 xn = *reinterpret_cast<const float4*>(xb + t + 4);  // prefetch
        LSTM_STEP(xq.x)
        LSTM_STEP(xq.y)
        LSTM_STEP(xq.z)
        LSTM_STEP(xq.w)
        xq = xn;
    }
    // final 4 steps (no prefetch)
    LSTM_STEP(xq.x)
    LSTM_STEP(xq.y)
    LSTM_STEP(xq.z)
    LSTM_STEP(xq.w)

#undef LSTM_STEP
#undef ACC

    // out[b] = dot(c, W_lin) + b_lin   (reduce across the 16-lane group)
    float v = act ? C * wl : 0.0f;
#pragma unroll
    for (int s = 1; s < 16; s <<= 1) v += __shfl_xor(v, s, 16);
    if (j16 == 0) out[b] = v + b_lin[0];
}

extern "C" void kernel_launch(void* const* d_in, const int* in_sizes, int n_in,
                              void* d_out, int out_size, void* d_ws, size_t ws_size,
                              hipStream_t stream) {
    const float* x     = (const float*)d_in[0];
    const float* W_ih  = (const float*)d_in[1];
    const float* W_hh  = (const float*)d_in[2];
    const float* b_ih  = (const float*)d_in[3];
    const float* b_hh  = (const float*)d_in[4];
    const float* W_lin = (const float*)d_in[5];
    const float* b_lin = (const float*)d_in[6];
    float* out = (float*)d_out;

    // 16 batch elements per 256-thread block -> 512 blocks, 2048 waves (2/SIMD).
    dim3 grid(B_TOT / 16), block(256);
    hipLaunchKernelGGL(lstm_fused_kernel, grid, block, 0, stream,
                       x, W_ih, W_hh, b_ih, b_hh, W_lin, b_lin, out);
}

// Round 5
// 333.427 us; speedup vs baseline: 1.1782x; 1.0698x over previous
//
#include <hip/hip_runtime.h>

#define B_TOT 8192
#define T_LEN 1024
#define HID 10
#define BPW 6   // batches per wave: lanes 0..59 active, 10 lanes per batch

typedef float v2f __attribute__((ext_vector_type(2)));

// Dense layout: wave = 6 batches x 10 hidden units (94% lane use vs 62.5%).
// h broadcast within each 10-lane group via ds_bpermute with a precomputed
// per-lane base address (LDS pipe, no VALU cost). Weights pre-scaled by the
// exp2 args; cell state kept as C = 2*log2(e)*c. Raw v_exp_f32/v_rcp_f32.
__global__ __launch_bounds__(64) void lstm_fused_kernel(
    const float* __restrict__ x,      // [B, T]
    const float* __restrict__ W_ih,   // [40, 1]
    const float* __restrict__ W_hh,   // [40, 10]  gate order i,f,g,o
    const float* __restrict__ b_ih,   // [40]
    const float* __restrict__ b_hh,   // [40]
    const float* __restrict__ W_lin,  // [1, 10]
    const float* __restrict__ b_lin,  // [1]
    float* __restrict__ out)          // [B]
{
    const int lane = threadIdx.x;          // 0..63
    const int grp  = lane / HID;           // 0..5 active, 6 for lanes 60..63
    const int j    = lane - grp * HID;     // hidden unit 0..9
    const int grpc = grp < BPW ? grp : BPW - 1;          // clamp idle lanes
    const int b    = blockIdx.x * BPW + grpc;
    const int bc   = b < B_TOT ? b : B_TOT - 1;          // clamp tail
    const bool act = (grp < BPW) && (b < B_TOT);

    const int pbase = 4 * HID * grpc;      // bpermute byte base of this group

    const float NL = -1.4426950408889634f; // -log2(e)  (sigmoid gates i,f,o)
    const float TL =  2.8853900817779268f; // 2*log2(e) (tanh gate g, C scale)

    // Per-lane pre-scaled weights, packed by gate pair (i,f) and (g,o).
    v2f w01[HID], w23[HID];
    v2f wi01, wi23, b01, b23;
    {
        const int r0 = 0 * HID + j, r1 = 1 * HID + j;
        const int r2 = 2 * HID + j, r3 = 3 * HID + j;
        wi01 = (v2f){NL * W_ih[r0], NL * W_ih[r1]};
        wi23 = (v2f){TL * W_ih[r2], NL * W_ih[r3]};
        b01  = (v2f){NL * (b_ih[r0] + b_hh[r0]), NL * (b_ih[r1] + b_hh[r1])};
        b23  = (v2f){TL * (b_ih[r2] + b_hh[r2]), NL * (b_ih[r3] + b_hh[r3])};
#pragma unroll
        for (int k = 0; k < HID; ++k) {
            w01[k] = (v2f){NL * W_hh[r0 * HID + k], NL * W_hh[r1 * HID + k]};
            w23[k] = (v2f){TL * W_hh[r2 * HID + k], NL * W_hh[r3 * HID + k]};
        }
    }
    // out = sum_j c_j*W_lin_j + b_lin; c = C/(2*log2 e) -> fold into wl.
    const float wl = W_lin[j] * 0.34657359027997264f;

    float h = 0.0f, C = 0.0f;
    const float* xb = x + (size_t)bc * T_LEN;

#define BC(K) __int_as_float(__builtin_amdgcn_ds_bpermute(pbase + 4 * (K), hbits))

#define ACC(K, HK, A01, A23)                                                  \
    {                                                                         \
        v2f hk2 = (v2f){(HK), (HK)};                                          \
        A01 = __builtin_elementwise_fma(w01[K], hk2, A01);                    \
        A23 = __builtin_elementwise_fma(w23[K], hk2, A23);                    \
    }

#define LSTM_STEP(xv)                                                         \
    {                                                                         \
        const int hbits = __float_as_int(h);                                  \
        float hk0 = BC(0), hk1 = BC(1), hk2_ = BC(2), hk3 = BC(3);            \
        float hk4 = BC(4), hk5 = BC(5), hk6 = BC(6), hk7 = BC(7);             \
        float hk8 = BC(8), hk9 = BC(9);                                       \
        v2f xv2 = (v2f){(xv), (xv)};                                          \
        v2f a01 = __builtin_elementwise_fma(xv2, wi01, b01);                  \
        v2f a23 = __builtin_elementwise_fma(xv2, wi23, b23);                  \
        v2f s01 = (v2f){0.0f, 0.0f}, s23 = (v2f){0.0f, 0.0f};                 \
        ACC(0, hk0, a01, a23) ACC(1, hk1, a01, a23) ACC(2, hk2_, a01, a23)    \
        ACC(3, hk3, a01, a23) ACC(4, hk4, a01, a23)                           \
        ACC(5, hk5, s01, s23) ACC(6, hk6, s01, s23) ACC(7, hk7, s01, s23)     \
        ACC(8, hk8, s01, s23) ACC(9, hk9, s01, s23)                           \
        a01 += s01;                                                           \
        a23 += s23;                                                           \
        float ig = __builtin_amdgcn_rcpf(1.0f + __builtin_amdgcn_exp2f(a01.x)); \
        float fg = __builtin_amdgcn_rcpf(1.0f + __builtin_amdgcn_exp2f(a01.y)); \
        float rg = __builtin_amdgcn_rcpf(1.0f + __builtin_amdgcn_exp2f(a23.x)); \
        float og = __builtin_amdgcn_rcpf(1.0f + __builtin_amdgcn_exp2f(a23.y)); \
        float gg = fmaf(-2.0f * TL, rg, TL);   /* 2L*tanh(g_raw) */           \
        C = fmaf(fg, C, ig * gg);                                             \
        float tc = fmaf(-2.0f,                                                \
                        __builtin_amdgcn_rcpf(1.0f + __builtin_amdgcn_exp2f(C)), \
                        1.0f);                                                \
        h = og * tc;                                                          \
    }

    float4 xq = *reinterpret_cast<const float4*>(xb);   // steps 0..3
    int t = 0;
    for (; t < T_LEN - 4; t += 4) {
        float4 xn = *reinterpret_cast<const float4*>(xb + t + 4);  // prefetch
        LSTM_STEP(xq.x)
        LSTM_STEP(xq.y)
        LSTM_STEP(xq.z)
        LSTM_STEP(xq.w)
        xq = xn;
    }
    LSTM_STEP(xq.x)
    LSTM_STEP(xq.y)
    LSTM_STEP(xq.z)
    LSTM_STEP(xq.w)

#undef LSTM_STEP
#undef ACC
#undef BC

    // Epilogue: out[b] = sum_j C_j * wl_j + b_lin  (reduce 10 lanes per group)
    __shared__ float red[64];
    red[lane] = act ? C * wl : 0.0f;
    __syncthreads();
    if (act && j == 0) {
        float s = b_lin[0];
#pragma unroll
        for (int u = 0; u < HID; ++u) s += red[grpc * HID + u];
        out[b] = s;
    }
}

extern "C" void kernel_launch(void* const* d_in, const int* in_sizes, int n_in,
                              void* d_out, int out_size, void* d_ws, size_t ws_size,
                              hipStream_t stream) {
    const float* x     = (const float*)d_in[0];
    const float* W_ih  = (const float*)d_in[1];
    const float* W_hh  = (const float*)d_in[2];
    const float* b_ih  = (const float*)d_in[3];
    const float* b_hh  = (const float*)d_in[4];
    const float* W_lin = (const float*)d_in[5];
    const float* b_lin = (const float*)d_in[6];
    float* out = (float*)d_out;

    // 6 batches per 64-thread block -> 1366 blocks (tail block guarded).
    dim3 grid((B_TOT + BPW - 1) / BPW), block(64);
    hipLaunchKernelGGL(lstm_fused_kernel, grid, block, 0, stream,
                       x, W_ih, W_hh, b_ih, b_hh, W_lin, b_lin, out);
}